// Round 14
// baseline (211.176 us; speedup 1.0000x reference)
//
#include <hip/hip_runtime.h>
#include <hip/hip_bf16.h>
#include <math.h>

#define EPS_  1e-8f
#define LNEPS 1e-5f

typedef __attribute__((ext_vector_type(8))) short   short8;
typedef __attribute__((ext_vector_type(8))) __bf16  bf16x8;
typedef __attribute__((ext_vector_type(4))) float   f32x4;
typedef unsigned short ushort_t;

__device__ __forceinline__ float bf2f(unsigned int u) { return __uint_as_float(u << 16); }
__device__ __forceinline__ unsigned short f2bf(float f) {
    unsigned int u = __float_as_uint(f);
    u += 0x7fff + ((u >> 16) & 1);
    return (unsigned short)(u >> 16);
}
__device__ __forceinline__ unsigned int cvt_pk_bf16(float lo, float hi) {
    unsigned int r;
    asm("v_cvt_pk_bf16_f32 %0, %1, %2" : "=v"(r) : "v"(lo), "v"(hi));
    return r;
}
__device__ __forceinline__ f32x4 mfma_bf16(short8 a, short8 b, f32x4 c) {
    union U { short8 s; bf16x8 b; };
    U ua, ub; ua.s = a; ub.s = b;
    return __builtin_amdgcn_mfma_f32_16x16x32_bf16(ua.b, ub.b, c, 0, 0, 0);
}
__device__ __forceinline__ float wred_sum(float v) {
#pragma unroll
    for (int off = 32; off > 0; off >>= 1) v += __shfl_xor(v, off);
    return v;
}

// -------- prepack Wk/Wv -> Wt[n][k] bf16 (k pre-scaled 0.125) --------
__global__ __launch_bounds__(256) void prepack_w_kernel(const float* __restrict__ Wk,
                                                        const float* __restrict__ Wv,
                                                        ushort_t* __restrict__ Wt) {
    int n = blockIdx.x;
    int k = threadIdx.x;
    float v = (n < 256) ? Wk[(size_t)k * 256 + n] * 0.125f : Wv[(size_t)k * 256 + (n - 256)];
    Wt[(size_t)n * 256 + k] = f2bf(v);
}

// -------- prepack Wt -> Wtp: per (wave,step,ni) 1KB block, lane-contiguous MFMA B-frags ----
__global__ __launch_bounds__(256) void prepack_wtp_kernel(const ushort_t* __restrict__ Wt,
                                                          ushort_t* __restrict__ Wtp) {
    int bs = blockIdx.x;              // wv*8+s, 0..63
    int wv = bs >> 3, s = bs & 7;
    int ni = threadIdx.x >> 6, l = threadIdx.x & 63;
    int n  = wv * 64 + ni * 16 + (l & 15);
    int k0 = s * 32 + (l >> 4) * 8;
    short8 v = *(const short8*)(Wt + (size_t)n * 256 + k0);
    *(short8*)(Wtp + ((size_t)bs * 4 + ni) * 512 + l * 8) = v;
}

// -------- prepack slot-chain weights to bf16 interleaved layouts --------
__global__ __launch_bounds__(512) void prepack_slotw_kernel(const float* __restrict__ w_ih,
                                                            const float* __restrict__ w_hh,
                                                            const float* __restrict__ w1,
                                                            const float* __restrict__ w2,
                                                            const float* __restrict__ Wq,
                                                            ushort_t* __restrict__ wg,
                                                            ushort_t* __restrict__ w1p,
                                                            ushort_t* __restrict__ w2q,
                                                            ushort_t* __restrict__ Wqp) {
    int t = threadIdx.x, bid = blockIdx.x, sec = blockIdx.y;
    if (sec == 0) {
        if (bid < 256) {
            int k = bid, c = t & 255;
            const float* src = (t >> 8) ? w_hh : w_ih;
            size_t o = ((size_t)k * 512 + t) * 4;
            wg[o + 0] = f2bf(src[(size_t)(0 * 256 + c) * 256 + k]);
            wg[o + 1] = f2bf(src[(size_t)(1 * 256 + c) * 256 + k]);
            wg[o + 2] = f2bf(src[(size_t)(2 * 256 + c) * 256 + k]);
            wg[o + 3] = 0;
        }
    } else if (sec == 1) {
        if (bid < 64) {
            size_t o = ((size_t)bid * 512 + t) * 4;
#pragma unroll
            for (int i = 0; i < 4; i++) w1p[o + i] = f2bf(w1[(size_t)(bid * 4 + i) * 512 + t]);
        }
    } else if (sec == 2) {
        if (bid < 64) {
            int k4g = bid * 2 + (t >> 8), c = t & 255;
            size_t o = ((size_t)k4g * 256 + c) * 4;
#pragma unroll
            for (int i = 0; i < 4; i++) w2q[o + i] = f2bf(w2[(size_t)(k4g * 4 + i) * 256 + c]);
        }
    } else {
        if (bid < 32) {
            int k4g = bid * 2 + (t >> 8), c = t & 255;
            size_t o = ((size_t)k4g * 256 + c) * 4;
#pragma unroll
            for (int i = 0; i < 4; i++) Wqp[o + i] = f2bf(Wq[(size_t)(k4g * 4 + i) * 256 + c]);
        }
    }
}

// -------- KV projection v8: K rows-major (kvK), V transposed (vT[d][token]) --------
// 1024 blocks x 512 threads (8 waves). Waves 0-3: K cols; waves 4-7: V cols (transposed out).
__global__ __launch_bounds__(512, 4) void kvproj_mfma_kernel(const float* __restrict__ in,
                                                             const float* __restrict__ g,
                                                             const float* __restrict__ bb,
                                                             const ushort_t* __restrict__ Wtp,
                                                             ushort_t* __restrict__ kvK,
                                                             ushort_t* __restrict__ vT) {
    __shared__ __align__(16) ushort_t As[64 * 256];
    const int tid = threadIdx.x;
    const int wv = tid >> 6, l = tid & 63;
    const int kc = l >> 4, lr = l & 15;
    const int m0 = blockIdx.x * 64;

    float4 g4 = *(const float4*)(g + l * 4);
    float4 b4 = *(const float4*)(bb + l * 4);
    float4 xv[8];
#pragma unroll
    for (int i = 0; i < 8; i++)
        xv[i] = *(const float4*)(in + (size_t)(m0 + i * 8 + wv) * 256 + l * 4);
#pragma unroll
    for (int i = 0; i < 8; i++) {
        float s1 = xv[i].x + xv[i].y + xv[i].z + xv[i].w;
        float s2 = xv[i].x * xv[i].x + xv[i].y * xv[i].y + xv[i].z * xv[i].z + xv[i].w * xv[i].w;
        s1 = wred_sum(s1);
        s2 = wred_sum(s2);
        float m = s1 * (1.0f / 256.0f);
        float r = rsqrtf(s2 * (1.0f / 256.0f) - m * m + LNEPS);
        float v0 = (xv[i].x - m) * r * g4.x + b4.x;
        float v1 = (xv[i].y - m) * r * g4.y + b4.y;
        float v2 = (xv[i].z - m) * r * g4.z + b4.z;
        float v3 = (xv[i].w - m) * r * g4.w + b4.w;
        uint2 pk = {cvt_pk_bf16(v0, v1), cvt_pk_bf16(v2, v3)};
        int row = i * 8 + wv;
        *(uint2*)&As[row * 256 + (((l >> 1) ^ (row & 15)) * 8) + (l & 1) * 4] = pk;
    }
    __syncthreads();

    f32x4 zero = {0.f, 0.f, 0.f, 0.f};
    f32x4 acc[4][4];
#pragma unroll
    for (int i = 0; i < 4; i++)
#pragma unroll
        for (int jj = 0; jj < 4; jj++) acc[i][jj] = zero;

    const ushort_t* wbase = Wtp + ((size_t)(wv * 8) * 4) * 512 + l * 8;
#pragma unroll
    for (int s = 0; s < 8; s++) {
        short8 bfr[4];
        const ushort_t* wpb = wbase + (size_t)s * 4 * 512;
#pragma unroll
        for (int ni = 0; ni < 4; ni++) bfr[ni] = *(const short8*)(wpb + ni * 512);
        short8 af[4];
#pragma unroll
        for (int mi = 0; mi < 4; mi++) {
            int r2 = lr + mi * 16;
            int c = s * 4 + kc;
            af[mi] = *(const short8*)&As[r2 * 256 + ((c ^ (r2 & 15)) * 8)];
        }
#pragma unroll
        for (int mi = 0; mi < 4; mi++)
#pragma unroll
            for (int ni = 0; ni < 4; ni++)
                acc[mi][ni] = mfma_bf16(af[mi], bfr[ni], acc[mi][ni]);
    }

    if (wv < 4) {
        // ---- K epilogue: paired-lane packed stores, kvK[token][256] ----
        const int odd = l & 1;
        const int colbase = wv * 64;
#pragma unroll
        for (int mi = 0; mi < 4; mi++)
#pragma unroll
            for (int ni = 0; ni < 4; ni++) {
                float s0 = odd ? acc[mi][ni][0] : acc[mi][ni][2];
                float s1_ = odd ? acc[mi][ni][1] : acc[mi][ni][3];
                float r0 = __shfl_xor(s0, 1);
                float r1_ = __shfl_xor(s1_, 1);
                int col0 = colbase + ni * 16 + (lr & ~1);
                unsigned int packA, packB;
                int rowA;
                if (!odd) {
                    packA = cvt_pk_bf16(acc[mi][ni][0], r0);
                    packB = cvt_pk_bf16(acc[mi][ni][1], r1_);
                    rowA = m0 + mi * 16 + kc * 4 + 0;
                } else {
                    packA = cvt_pk_bf16(r0, acc[mi][ni][2]);
                    packB = cvt_pk_bf16(r1_, acc[mi][ni][3]);
                    rowA = m0 + mi * 16 + kc * 4 + 2;
                }
                *(unsigned int*)(kvK + (size_t)rowA * 256 + col0) = packA;
                *(unsigned int*)(kvK + (size_t)(rowA + 1) * 256 + col0) = packB;
            }
    } else {
        // ---- V epilogue: transposed, vT[b*256 + d][1024 tokens], 4 tokens packed/lane ----
        const int bI = m0 >> 10;
        const int tbase = m0 & 1023;
#pragma unroll
        for (int mi = 0; mi < 4; mi++)
#pragma unroll
            for (int ni = 0; ni < 4; ni++) {
                int d = (wv - 4) * 64 + ni * 16 + lr;
                int tok = tbase + mi * 16 + kc * 4;
                uint2 pk;
                pk.x = cvt_pk_bf16(acc[mi][ni][0], acc[mi][ni][1]);
                pk.y = cvt_pk_bf16(acc[mi][ni][2], acc[mi][ni][3]);
                *(uint2*)(vT + ((size_t)bI * 256 + d) * 1024 + tok) = pk;
            }
    }
}

// -------- initial slot LN + q projection (once). grid 512 x 256 --------
__global__ __launch_bounds__(256) void qproj_kernel(const float* __restrict__ slots,
                                                    const float* __restrict__ g,
                                                    const float* __restrict__ bvec,
                                                    const float* __restrict__ Wq,
                                                    float* __restrict__ qp) {
    int row = blockIdx.x;
    int tid = threadIdx.x;
    __shared__ float s_s[256];
    __shared__ float red[8];
    float x = slots[(size_t)row * 256 + tid];
    float s1 = wred_sum(x);
    float s2 = wred_sum(x * x);
    if ((tid & 63) == 0) { red[tid >> 6] = s1; red[4 + (tid >> 6)] = s2; }
    __syncthreads();
    float m  = (red[0] + red[1] + red[2] + red[3]) * (1.0f / 256.0f);
    float e2 = (red[4] + red[5] + red[6] + red[7]) * (1.0f / 256.0f);
    float rst = rsqrtf(e2 - m * m + LNEPS);
    s_s[tid] = (x - m) * rst * g[tid] + bvec[tid];
    __syncthreads();
    float acc = 0.f;
#pragma unroll 4
    for (int d = 0; d < 256; d++) acc += s_s[d] * Wq[(size_t)d * 256 + tid];
    int b = row >> 3, q = row & 7;
    qp[((size_t)(b * 4 + (tid >> 6)) * 8 + q) * 64 + (tid & 63)] = acc;
}

// -------- fused attention v6: MFMA logits + softmax + MFMA PV (transposed V) --------
// grid (8 chunks of 128 tokens, 64 b) x 256 threads (4 waves; wave w = head h).
__global__ __launch_bounds__(256) void attn_fused_kernel(const ushort_t* __restrict__ kvK,
                                                         const ushort_t* __restrict__ vT,
                                                         const float* __restrict__ qp,
                                                         float* __restrict__ Upart,
                                                         float* __restrict__ Cpart,
                                                         float* __restrict__ vis,
                                                         int write_vis) {
    int b = blockIdx.y;
    int chunk = blockIdx.x;
    int tid = threadIdx.x;
    __shared__ __align__(16) ushort_t qfrag[16 * 512];   // 16 KB
    __shared__ float att[128][33];                       // 16.9 KB (padded: no bank conflict)
    __shared__ __align__(16) ushort_t attT[64][136];     // 17.4 KB bf16 P^T, rows h*16+q
    __shared__ float cred[8][32];

    {
        const float* qb_ = qp + (size_t)b * 2048;
#pragma unroll
        for (int snt = 0; snt < 16; snt++) {
            int s = snt >> 1, nt = snt & 1;
#pragma unroll
            for (int rep = 0; rep < 2; rep++) {
                int idx = tid + rep * 256;  // 0..511
                int k  = s * 32 + ((idx >> 7) << 3) + (idx & 7);
                int hq = nt * 16 + ((idx >> 3) & 15);
                float v = ((k >> 6) == (hq >> 3))
                              ? qb_[(hq >> 3) * 512 + (hq & 7) * 64 + (k & 63)] : 0.f;
                qfrag[snt * 512 + idx] = f2bf(v);
            }
        }
        // zero the pad rows (q=8..15 per head) of attT: 32 rows x 68 uints
        for (int idx = tid; idx < 32 * 68; idx += 256) {
            int z = idx / 68, j = idx - z * 68;
            int row = (z >> 3) * 16 + 8 + (z & 7);
            *(unsigned int*)&attT[row][j * 2] = 0u;
        }
    }
    __syncthreads();

    const int w = tid >> 6, l = tid & 63;
    const int lr = l & 15, kc = l >> 4, kc8 = kc * 8;

    // ---- phase A: logits via MFMA (kvK stride 256) ----
    short8 qb2[2][8];
#pragma unroll
    for (int s = 0; s < 8; s++) {
        qb2[0][s] = *(const short8*)&qfrag[(s * 2 + 0) * 512 + l * 8];
        qb2[1][s] = *(const short8*)&qfrag[(s * 2 + 1) * 512 + l * 8];
    }
    f32x4 zero = {0.f, 0.f, 0.f, 0.f};
#pragma unroll
    for (int mi_loc = 0; mi_loc < 2; mi_loc++) {
        int mi = w * 2 + mi_loc;
        f32x4 a0 = zero, a1 = zero;
        const ushort_t* abase = kvK + (size_t)(b * 1024 + chunk * 128 + mi * 16 + lr) * 256 + kc8;
#pragma unroll
        for (int s = 0; s < 8; s++) {
            short8 af = *(const short8*)(abase + s * 32);
            a0 = mfma_bf16(af, qb2[0][s], a0);
            a1 = mfma_bf16(af, qb2[1][s], a1);
        }
        int row0 = mi * 16 + kc * 4;
#pragma unroll
        for (int r = 0; r < 4; r++) {
            att[row0 + r][lr]      = a0[r];
            att[row0 + r][16 + lr] = a1[r];
        }
    }
    __syncthreads();

    // ---- softmax (2 threads/token); write attE f32 (for colsum) + bf16 P^T ----
    {
        int token = tid >> 1, half = tid & 1;
        float v[16];
        float mx = -3.4e38f;
#pragma unroll
        for (int j = 0; j < 16; j++) { v[j] = att[token][half * 16 + j]; mx = fmaxf(mx, v[j]); }
        mx = fmaxf(mx, __shfl_xor(mx, 1));
        float sm = 0.f;
#pragma unroll
        for (int j = 0; j < 16; j++) { v[j] = __expf(v[j] - mx); sm += v[j]; }
        sm += __shfl_xor(sm, 1);
        float inv = 1.0f / sm;
#pragma unroll
        for (int j = 0; j < 16; j++) {
            v[j] = v[j] * inv + EPS_;
            att[token][half * 16 + j] = v[j];
            int hq = half * 16 + j;
            attT[(hq >> 3) * 16 + (hq & 7)][token] = f2bf(v[j]);
        }
        if (write_vis) {
#pragma unroll
            for (int q = 0; q < 8; q++) {
                float pv = (v[q] - EPS_) + (v[q + 8] - EPS_);
                float pf = pv + __shfl_xor(pv, 1);
                if (half == 0) vis[(size_t)(b * 8 + q) * 1024 + chunk * 128 + token] = pf;
            }
        }
    }
    __syncthreads();

    // ---- column sums -> Cpart ----
    {
        int hq2 = tid & 31, grp = tid >> 5;
        float s = 0.f;
#pragma unroll
        for (int i = 0; i < 16; i++) s += att[grp * 16 + i][hq2];
        cred[grp][hq2] = s;
    }
    __syncthreads();
    if (tid < 32) {
        float s = 0.f;
#pragma unroll
        for (int g2 = 0; g2 < 8; g2++) s += cred[g2][tid];
        Cpart[(size_t)(b * 8 + chunk) * 32 + tid] = s;
    }

    // ---- phase B: wave w = head h; U(16x64) = P^T(16x128) @ V(128x64) via MFMA ----
    {
        const int h = w;
        f32x4 acc[4];
#pragma unroll
        for (int nt = 0; nt < 4; nt++) acc[nt] = zero;
        const ushort_t* vrow = vT + ((size_t)b * 256 + h * 64) * 1024 + chunk * 128 + kc8;
#pragma unroll
        for (int ks = 0; ks < 4; ks++) {
            short8 afr = *(const short8*)&attT[h * 16 + lr][ks * 32 + kc8];
#pragma unroll
            for (int nt = 0; nt < 4; nt++) {
                short8 bfr = *(const short8*)(vrow + (size_t)(nt * 16 + lr) * 1024 + ks * 32);
                acc[nt] = mfma_bf16(afr, bfr, acc[nt]);
            }
        }
        if (kc < 2) {
            float* up = Upart + (size_t)(b * 8 + chunk) * 2048 + h * 64;
#pragma unroll
            for (int nt = 0; nt < 4; nt++)
#pragma unroll
                for (int r = 0; r < 4; r++) {
                    int q = kc * 4 + r;
                    up[q * 256 + nt * 16 + lr] = acc[nt][r];
                }
        }
    }
}

// -------- fused slot update v4 (unchanged from round 13) --------
// 256 blocks x 1024 threads; 2 rows per block.
__global__ __launch_bounds__(1024) void slot_fused_kernel(const float* __restrict__ Upart,
                                                          const float* __restrict__ Cpart,
                                                          const float* __restrict__ slotsIn,
                                                          const ushort_t* __restrict__ wg,
                                                          const float* __restrict__ b_ih,
                                                          const float* __restrict__ b_hh,
                                                          const float* __restrict__ ln_mlp_g,
                                                          const float* __restrict__ ln_mlp_b,
                                                          const ushort_t* __restrict__ w1p,
                                                          const float* __restrict__ b1,
                                                          const ushort_t* __restrict__ w2q,
                                                          const float* __restrict__ b2,
                                                          const float* __restrict__ ln_sl_g,
                                                          const float* __restrict__ ln_sl_b,
                                                          const ushort_t* __restrict__ Wqp,
                                                          float* __restrict__ slotsOut,
                                                          float* __restrict__ qp,
                                                          int emit_qp) {
    __shared__ float U_s[2][256], H_s[2][256];
    __shared__ float rsum[2][2][256];
    __shared__ float gpart[2][12][256];
    __shared__ float SB_s[2][256], M_s[2][256];
    __shared__ float hid_s[2][512];
    __shared__ float mpart[2][2][512];
    __shared__ float ppart[4][2][256];
    __shared__ float redA[8], redB[8];
    const int t = threadIdx.x;
    const int kh = t >> 9, s9 = t & 511;
    const int rr = s9 >> 8, c = s9 & 255;
    const int lane = t & 63, wvi = t >> 6;
    const int r0 = blockIdx.x * 2;
    const int rg = r0 + rr, bb_ = rg >> 3, q = rg & 7;

    {
        float s = 0.f;
#pragma unroll
        for (int p2 = 0; p2 < 4; p2++)
            s += Upart[(size_t)(bb_ * 8 + kh * 4 + p2) * 2048 + q * 256 + c];
        rsum[kh][rr][c] = s;
    }
    __syncthreads();
    if (kh == 0) {
        int h = c >> 6;
        float C = 0.f;
#pragma unroll
        for (int p2 = 0; p2 < 8; p2++)
            C += Cpart[(size_t)(bb_ * 8 + p2) * 32 + h * 8 + q];
        U_s[rr][c] = (rsum[0][rr][c] + rsum[1][rr][c]) / C;
        H_s[rr][c] = slotsIn[(size_t)rg * 256 + c];
    }
    __syncthreads();

    {
        float ar0, az0, an0;
        if (kh == 0) {
            const float* bias = rr ? b_hh : b_ih;
            ar0 = bias[c]; az0 = bias[256 + c]; an0 = bias[512 + c];
        } else { ar0 = az0 = an0 = 0.f; }
        float ar1 = ar0, az1 = az0, an1 = an0;
        const float (*act)[256] = rr ? H_s : U_s;
        const ushort_t* wp = wg + (size_t)s9 * 4;
        for (int cc = 0; cc < 8; cc++) {
            uint2 wreg[16];
#pragma unroll
            for (int i = 0; i < 16; i++) {
                int k = kh * 128 + cc * 16 + i;
                wreg[i] = *(const uint2*)(wp + (size_t)k * 2048);
            }
#pragma unroll
            for (int i = 0; i < 16; i++) {
                int k = kh * 128 + cc * 16 + i;
                float w0  = bf2f(wreg[i].x & 0xffffu);
                float w1_ = bf2f(wreg[i].x >> 16);
                float w2_ = bf2f(wreg[i].y & 0xffffu);
                float a0 = act[0][k], a1 = act[1][k];
                ar0 += a0 * w0; az0 += a0 * w1_; an0 += a0 * w2_;
                ar1 += a1 * w0; az1 += a1 * w1_; an1 += a1 * w2_;
            }
        }
        gpart[kh][rr * 6 + 0][c] = ar0; gpart[kh][rr * 6 + 1][c] = ar1;
        gpart[kh][rr * 6 + 2][c] = az0; gpart[kh][rr * 6 + 3][c] = az1;
        gpart[kh][rr * 6 + 4][c] = an0; gpart[kh][rr * 6 + 5][c] = an1;
    }
    __syncthreads();

    float sb = 0.f;
    if (kh == 0) {
        float xr = gpart[0][0 + rr][c] + gpart[1][0 + rr][c];
        float xz = gpart[0][2 + rr][c] + gpart[1][2 + rr][c];
        float xn = gpart[0][4 + rr][c] + gpart[1][4 + rr][c];
        float hr = gpart[0][6 + rr][c] + gpart[1][6 + rr][c];
        float hz = gpart[0][8 + rr][c] + gpart[1][8 + rr][c];
        float hn = gpart[0][10 + rr][c] + gpart[1][10 + rr][c];
        float rg_ = 1.f / (1.f + __expf(-(xr + hr)));
        float z   = 1.f / (1.f + __expf(-(xz + hz)));
        float nn  = tanhf(xn + rg_ * hn);
        sb = (1.f - z) * nn + z * H_s[rr][c];
        SB_s[rr][c] = sb;
        float s1 = wred_sum(sb), s2 = wred_sum(sb * sb);
        if (lane == 0) { redA[wvi] = s1; redB[wvi] = s2; }
    }
    __syncthreads();
    if (kh == 0) {
        int base = rr * 4;
        float m  = (redA[base] + redA[base + 1] + redA[base + 2] + redA[base + 3]) * (1.f / 256.f);
        float e2 = (redB[base] + redB[base + 1] + redB[base + 2] + redB[base + 3]) * (1.f / 256.f);
        float rst = rsqrtf(e2 - m * m + LNEPS);
        M_s[rr][c] = (sb - m) * rst * ln_mlp_g[c] + ln_mlp_b[c];
    }
    __syncthreads();

    {
        float h10 = 0.f, h11 = 0.f;
        const ushort_t* wp = w1p + (size_t)s9 * 4;
        for (int cc = 0; cc < 2; cc++) {
            uint2 wreg[16];
#pragma unroll
            for (int i = 0; i < 16; i++) {
                int k4 = kh * 32 + cc * 16 + i;
                wreg[i] = *(const uint2*)(wp + (size_t)k4 * 2048);
            }
#pragma unroll
            for (int i = 0; i < 16; i++) {
                int k4 = kh * 32 + cc * 16 + i;
                float wA[4] = {bf2f(wreg[i].x & 0xffffu), bf2f(wreg[i].x >> 16),
                               bf2f(wreg[i].y & 0xffffu), bf2f(wreg[i].y >> 16)};
#pragma unroll
                for (int ii = 0; ii < 4; ii++) {
                    int k = k4 * 4 + ii;
                    h10 += M_s[0][k] * wA[ii];
                    h11 += M_s[1][k] * wA[ii];
                }
            }
        }
        mpart[kh][0][s9] = h10;
        mpart[kh][1][s9] = h11;
    }
    __syncthreads();
    if (kh == 0) {
        float bb1 = b1[s9];
        hid_s[0][s9] = fmaxf(mpart[0][0][s9] + mpart[1][0][s9] + bb1, 0.f);
        hid_s[1][s9] = fmaxf(mpart[0][1][s9] + mpart[1][1][s9] + bb1, 0.f);
    }
    __syncthreads();

    {
        int q2 = kh * 2 + rr;
        float p0 = 0.f, p1 = 0.f;
        const ushort_t* wp = w2q + (size_t)c * 4;
        for (int cc = 0; cc < 2; cc++) {
            uint2 wreg[16];
#pragma unroll
            for (int i = 0; i < 16; i++) {
                int k4g = q2 * 32 + cc * 16 + i;
                wreg[i] = *(const uint2*)(wp + (size_t)k4g * 1024);
            }
#pragma unroll
            for (int i = 0; i < 16; i++) {
                int k4g = q2 * 32 + cc * 16 + i;
                float wA[4] = {bf2f(wreg[i].x & 0xffffu), bf2f(wreg[i].x >> 16),
                               bf2f(wreg[i].y & 0xffffu), bf2f(wreg[i].y >> 16)};
#pragma unroll
                for (int ii = 0; ii < 4; ii++) {
                    int k = k4g * 4 + ii;
                    p0 += hid_s[0][k] * wA[ii];
                    p1 += hid_s[1][k] * wA[ii];
                }
            }
        }
        ppart[q2][0][c] = p0;
        ppart[q2][1][c] = p1;
    }
    __syncthreads();
    float outv = 0.f;
    if (kh == 0) {
        outv = ppart[0][rr][c] + ppart[1][rr][c] + ppart[2][rr][c] + ppart[3][rr][c]
             + b2[c] + SB_s[rr][c];
        slotsOut[(size_t)rg * 256 + c] = outv;
    }

    if (emit_qp) {
        __syncthreads();
        if (kh == 0) {
            float s1 = wred_sum(outv), s2 = wred_sum(outv * outv);
            if (lane == 0) { redA[wvi] = s1; redB[wvi] = s2; }
        }
        __syncthreads();
        if (kh == 0) {
            int base = rr * 4;
            float m  = (redA[base] + redA[base + 1] + redA[base + 2] + redA[base + 3]) * (1.f / 256.f);
            float e2 = (redB[base] + redB[base + 1] + redB[base + 2] + redB[base + 3]) * (1.f / 256.f);
            float rst = rsqrtf(e2 - m * m + LNEPS);
            M_s[rr][c] = (outv - m) * rst * ln_sl_g[c] + ln_sl_b[c];
        }
        __syncthreads();
        {
            int q2 = kh * 2 + rr;
            float p0 = 0.f, p1 = 0.f;
            const ushort_t* wp = Wqp + (size_t)c * 4;
            uint2 wreg[16];
#pragma unroll
            for (int i = 0; i < 16; i++) {
                int k4g = q2 * 16 + i;
                wreg[i] = *(const uint2*)(wp + (size_t)k4g * 1024);
            }
#pragma unroll
            for (int i = 0; i < 16; i++) {
                int k4g = q2 * 16 + i;
                float wA[4] = {bf2f(wreg[i].x & 0xffffu), bf2f(wreg[i].x >> 16),
                               bf2f(wreg[i].y & 0xffffu), bf2f(wreg[i].y >> 16)};
#pragma unroll
                for (int ii = 0; ii < 4; ii++) {
                    int k = k4g * 4 + ii;
                    p0 += M_s[0][k] * wA[ii];
                    p1 += M_s[1][k] * wA[ii];
                }
            }
            ppart[q2][0][c] = p0;
            ppart[q2][1][c] = p1;
        }
        __syncthreads();
        if (kh == 0) {
            float qv = ppart[0][rr][c] + ppart[1][rr][c] + ppart[2][rr][c] + ppart[3][rr][c];
            qp[(size_t)bb_ * 2048 + (c >> 6) * 512 + q * 64 + (c & 63)] = qv;
        }
    }
}

// -------- host --------
extern "C" void kernel_launch(void* const* d_in, const int* in_sizes, int n_in,
                              void* d_out, int out_size, void* d_ws, size_t ws_size,
                              hipStream_t stream) {
    const float* inputs   = (const float*)d_in[0];
    const float* slots0   = (const float*)d_in[1];
    const float* ln_in_g  = (const float*)d_in[2];
    const float* ln_in_b  = (const float*)d_in[3];
    const float* ln_sl_g  = (const float*)d_in[4];
    const float* ln_sl_b  = (const float*)d_in[5];
    const float* ln_mlp_g = (const float*)d_in[6];
    const float* ln_mlp_b = (const float*)d_in[7];
    const float* Wq       = (const float*)d_in[8];
    const float* Wk       = (const float*)d_in[9];
    const float* Wv       = (const float*)d_in[10];
    const float* w_ih     = (const float*)d_in[11];
    const float* w_hh     = (const float*)d_in[12];
    const float* b_ih     = (const float*)d_in[13];
    const float* b_hh     = (const float*)d_in[14];
    const float* w1       = (const float*)d_in[15];
    const float* b1       = (const float*)d_in[16];
    const float* w2       = (const float*)d_in[17];
    const float* b2       = (const float*)d_in[18];

    float* out_slots = (float*)d_out;
    float* out_vis   = (float*)d_out + 64 * 8 * 256;

    char* p = (char*)d_ws;
    auto carve = [&](size_t bytes) {
        void* r = (void*)p;
        p += (bytes + 255) & ~(size_t)255;
        return r;
    };
    ushort_t* kvK  = (ushort_t*)carve((size_t)65536 * 256 * 2);   // 32 MB (K)
    ushort_t* vT   = (ushort_t*)carve((size_t)64 * 256 * 1024 * 2); // 32 MB (V^T)
    ushort_t* Wt   = (ushort_t*)carve((size_t)512 * 256 * 2);
    ushort_t* Wtp  = (ushort_t*)carve((size_t)512 * 256 * 2);
    ushort_t* wg   = (ushort_t*)carve((size_t)256 * 512 * 4 * 2);
    ushort_t* w1p  = (ushort_t*)carve((size_t)64 * 512 * 4 * 2);
    ushort_t* w2q  = (ushort_t*)carve((size_t)128 * 256 * 4 * 2);
    ushort_t* Wqp  = (ushort_t*)carve((size_t)64 * 256 * 4 * 2);
    float* qp      = (float*)carve((size_t)64 * 2048 * 4);
    float* Upart   = (float*)carve((size_t)64 * 8 * 2048 * 4);    // 4 MB
    float* Cpart   = (float*)carve((size_t)64 * 8 * 32 * 4);
    float* slotsA  = (float*)carve((size_t)512 * 256 * 4);

    prepack_w_kernel<<<512, 256, 0, stream>>>(Wk, Wv, Wt);
    prepack_wtp_kernel<<<64, 256, 0, stream>>>(Wt, Wtp);
    prepack_slotw_kernel<<<dim3(256, 4), 512, 0, stream>>>(w_ih, w_hh, w1, w2, Wq,
                                                           wg, w1p, w2q, Wqp);
    kvproj_mfma_kernel<<<1024, 512, 0, stream>>>(inputs, ln_in_g, ln_in_b, Wtp, kvK, vT);
    qproj_kernel<<<512, 256, 0, stream>>>(slots0, ln_sl_g, ln_sl_b, Wq, qp);

    for (int it = 0; it < 3; ++it) {
        attn_fused_kernel<<<dim3(8, 64), 256, 0, stream>>>(kvK, vT, qp, Upart, Cpart,
                                                           out_vis, (it == 2) ? 1 : 0);
        slot_fused_kernel<<<256, 1024, 0, stream>>>(
            Upart, Cpart, (it == 0) ? slots0 : slotsA,
            wg, b_ih, b_hh, ln_mlp_g, ln_mlp_b, w1p, b1, w2q, b2,
            ln_sl_g, ln_sl_b, Wqp,
            (it == 2) ? out_slots : slotsA, qp, (it < 2) ? 1 : 0);
    }
}

// Round 16
// 178.174 us; speedup vs baseline: 1.1852x; 1.1852x over previous
//
#include <hip/hip_runtime.h>
#include <hip/hip_bf16.h>
#include <math.h>

#define EPS_  1e-8f
#define LNEPS 1e-5f

typedef __attribute__((ext_vector_type(8))) short    short8;
typedef __attribute__((ext_vector_type(8))) __bf16   bf16x8;
typedef __attribute__((ext_vector_type(4))) float    f32x4;
typedef __attribute__((ext_vector_type(2))) _Float16 h16x2;
typedef __attribute__((ext_vector_type(2))) __fp16   fp16x2;
typedef unsigned short ushort_t;

__device__ __forceinline__ float bf2f(unsigned int u) { return __uint_as_float(u << 16); }
__device__ __forceinline__ unsigned short f2bf(float f) {
    unsigned int u = __float_as_uint(f);
    u += 0x7fff + ((u >> 16) & 1);
    return (unsigned short)(u >> 16);
}
__device__ __forceinline__ unsigned int cvt_pk_bf16(float lo, float hi) {
    unsigned int r;
    asm("v_cvt_pk_bf16_f32 %0, %1, %2" : "=v"(r) : "v"(lo), "v"(hi));
    return r;
}
__device__ __forceinline__ unsigned int pkh(float a, float b) {
    union { fp16x2 h; unsigned int u; } x;
    x.h = __builtin_amdgcn_cvt_pkrtz(a, b);
    return x.u;
}
__device__ __forceinline__ float fdot2(unsigned int a, unsigned int b, float c) {
    union { unsigned int u; h16x2 h; } xa, xb;
    xa.u = a; xb.u = b;
    return __builtin_amdgcn_fdot2(xa.h, xb.h, c, false);
}
__device__ __forceinline__ f32x4 mfma_bf16(short8 a, short8 b, f32x4 c) {
    union U { short8 s; bf16x8 b; };
    U ua, ub; ua.s = a; ub.s = b;
    return __builtin_amdgcn_mfma_f32_16x16x32_bf16(ua.b, ub.b, c, 0, 0, 0);
}
__device__ __forceinline__ float wred_sum(float v) {
#pragma unroll
    for (int off = 32; off > 0; off >>= 1) v += __shfl_xor(v, off);
    return v;
}

// -------- prepack Wk/Wv -> Wt[n][k] bf16 (k pre-scaled 0.125) --------
__global__ __launch_bounds__(256) void prepack_w_kernel(const float* __restrict__ Wk,
                                                        const float* __restrict__ Wv,
                                                        ushort_t* __restrict__ Wt) {
    int n = blockIdx.x;
    int k = threadIdx.x;
    float v = (n < 256) ? Wk[(size_t)k * 256 + n] * 0.125f : Wv[(size_t)k * 256 + (n - 256)];
    Wt[(size_t)n * 256 + k] = f2bf(v);
}

// -------- prepack Wt -> Wtp: per (wave,step,ni) 1KB block, lane-contiguous MFMA B-frags ----
__global__ __launch_bounds__(256) void prepack_wtp_kernel(const ushort_t* __restrict__ Wt,
                                                          ushort_t* __restrict__ Wtp) {
    int bs = blockIdx.x;              // wv*8+s, 0..63
    int wv = bs >> 3, s = bs & 7;
    int ni = threadIdx.x >> 6, l = threadIdx.x & 63;
    int n  = wv * 64 + ni * 16 + (l & 15);
    int k0 = s * 32 + (l >> 4) * 8;
    short8 v = *(const short8*)(Wt + (size_t)n * 256 + k0);
    *(short8*)(Wtp + ((size_t)bs * 4 + ni) * 512 + l * 8) = v;
}

// -------- prepack slot-chain weights to PACKED F16 PAIRS over k --------
__global__ __launch_bounds__(512) void prepack_slotw_kernel(const float* __restrict__ w_ih,
                                                            const float* __restrict__ w_hh,
                                                            const float* __restrict__ w1,
                                                            const float* __restrict__ w2,
                                                            const float* __restrict__ Wq,
                                                            unsigned int* __restrict__ wgp,
                                                            unsigned int* __restrict__ w1pp,
                                                            unsigned int* __restrict__ w2pp,
                                                            unsigned int* __restrict__ Wqpp) {
    int t = threadIdx.x, bid = blockIdx.x, sec = blockIdx.y;
    if (sec == 0) {
        if (bid < 128) {
            int c = t & 255;
            const float* src = (t >> 8) ? w_hh : w_ih;
            uint4 o;
            unsigned int* po = (unsigned int*)&o;
#pragma unroll
            for (int g = 0; g < 3; g++) {
                const float* row = src + (size_t)(g * 256 + c) * 256 + 2 * bid;
                po[g] = pkh(row[0], row[1]);
            }
            o.w = 0;
            *(uint4*)&wgp[((size_t)bid * 512 + t) * 4] = o;
        }
    } else if (sec == 1) {
        if (bid < 128) {
            float a = w1[(size_t)(2 * bid) * 512 + t];
            float b = w1[(size_t)(2 * bid + 1) * 512 + t];
            w1pp[(size_t)bid * 512 + t] = pkh(a, b);
        }
    } else if (sec == 2) {
        if (bid < 256 && t < 256) {
            float a = w2[(size_t)(2 * bid) * 256 + t];
            float b = w2[(size_t)(2 * bid + 1) * 256 + t];
            w2pp[(size_t)bid * 256 + t] = pkh(a, b);
        }
    } else {
        if (bid < 128 && t < 256) {
            float a = Wq[(size_t)(2 * bid) * 256 + t];
            float b = Wq[(size_t)(2 * bid + 1) * 256 + t];
            Wqpp[(size_t)bid * 256 + t] = pkh(a, b);
        }
    }
}

// -------- KV projection v7 (round 12, unchanged) --------
__global__ __launch_bounds__(512, 4) void kvproj_mfma_kernel(const float* __restrict__ in,
                                                             const float* __restrict__ g,
                                                             const float* __restrict__ bb,
                                                             const ushort_t* __restrict__ Wtp,
                                                             ushort_t* __restrict__ kvout) {
    __shared__ __align__(16) ushort_t As[64 * 256];
    const int tid = threadIdx.x;
    const int wv = tid >> 6, l = tid & 63;
    const int kc = l >> 4, lr = l & 15;
    const int m0 = blockIdx.x * 64;

    float4 g4 = *(const float4*)(g + l * 4);
    float4 b4 = *(const float4*)(bb + l * 4);
    float4 xv[8];
#pragma unroll
    for (int i = 0; i < 8; i++)
        xv[i] = *(const float4*)(in + (size_t)(m0 + i * 8 + wv) * 256 + l * 4);
#pragma unroll
    for (int i = 0; i < 8; i++) {
        float s1 = xv[i].x + xv[i].y + xv[i].z + xv[i].w;
        float s2 = xv[i].x * xv[i].x + xv[i].y * xv[i].y + xv[i].z * xv[i].z + xv[i].w * xv[i].w;
        s1 = wred_sum(s1);
        s2 = wred_sum(s2);
        float m = s1 * (1.0f / 256.0f);
        float r = rsqrtf(s2 * (1.0f / 256.0f) - m * m + LNEPS);
        float v0 = (xv[i].x - m) * r * g4.x + b4.x;
        float v1 = (xv[i].y - m) * r * g4.y + b4.y;
        float v2 = (xv[i].z - m) * r * g4.z + b4.z;
        float v3 = (xv[i].w - m) * r * g4.w + b4.w;
        uint2 pk = {cvt_pk_bf16(v0, v1), cvt_pk_bf16(v2, v3)};
        int row = i * 8 + wv;
        *(uint2*)&As[row * 256 + (((l >> 1) ^ (row & 15)) * 8) + (l & 1) * 4] = pk;
    }
    __syncthreads();

    f32x4 zero = {0.f, 0.f, 0.f, 0.f};
    f32x4 acc[4][4];
#pragma unroll
    for (int i = 0; i < 4; i++)
#pragma unroll
        for (int jj = 0; jj < 4; jj++) acc[i][jj] = zero;

    const ushort_t* wbase = Wtp + ((size_t)(wv * 8) * 4) * 512 + l * 8;
#pragma unroll
    for (int s = 0; s < 8; s++) {
        short8 bfr[4];
        const ushort_t* wpb = wbase + (size_t)s * 4 * 512;
#pragma unroll
        for (int ni = 0; ni < 4; ni++) bfr[ni] = *(const short8*)(wpb + ni * 512);
        short8 af[4];
#pragma unroll
        for (int mi = 0; mi < 4; mi++) {
            int r2 = lr + mi * 16;
            int c = s * 4 + kc;
            af[mi] = *(const short8*)&As[r2 * 256 + ((c ^ (r2 & 15)) * 8)];
        }
#pragma unroll
        for (int mi = 0; mi < 4; mi++)
#pragma unroll
            for (int ni = 0; ni < 4; ni++)
                acc[mi][ni] = mfma_bf16(af[mi], bfr[ni], acc[mi][ni]);
    }

    const int odd = l & 1;
    const int colbase = wv * 64;
#pragma unroll
    for (int mi = 0; mi < 4; mi++)
#pragma unroll
        for (int ni = 0; ni < 4; ni++) {
            float s0 = odd ? acc[mi][ni][0] : acc[mi][ni][2];
            float s1_ = odd ? acc[mi][ni][1] : acc[mi][ni][3];
            float r0 = __shfl_xor(s0, 1);
            float r1_ = __shfl_xor(s1_, 1);
            int col0 = colbase + ni * 16 + (lr & ~1);
            unsigned int packA, packB;
            int rowA;
            if (!odd) {
                packA = cvt_pk_bf16(acc[mi][ni][0], r0);
                packB = cvt_pk_bf16(acc[mi][ni][1], r1_);
                rowA = m0 + mi * 16 + kc * 4 + 0;
            } else {
                packA = cvt_pk_bf16(r0, acc[mi][ni][2]);
                packB = cvt_pk_bf16(r1_, acc[mi][ni][3]);
                rowA = m0 + mi * 16 + kc * 4 + 2;
            }
            *(unsigned int*)(kvout + (size_t)rowA * 512 + col0) = packA;
            *(unsigned int*)(kvout + (size_t)(rowA + 1) * 512 + col0) = packB;
        }
}

// -------- initial slot LN + q projection (once). grid 512 x 256 --------
__global__ __launch_bounds__(256) void qproj_kernel(const float* __restrict__ slots,
                                                    const float* __restrict__ g,
                                                    const float* __restrict__ bvec,
                                                    const float* __restrict__ Wq,
                                                    float* __restrict__ qp) {
    int row = blockIdx.x;
    int tid = threadIdx.x;
    __shared__ float s_s[256];
    __shared__ float red[8];
    float x = slots[(size_t)row * 256 + tid];
    float s1 = wred_sum(x);
    float s2 = wred_sum(x * x);
    if ((tid & 63) == 0) { red[tid >> 6] = s1; red[4 + (tid >> 6)] = s2; }
    __syncthreads();
    float m  = (red[0] + red[1] + red[2] + red[3]) * (1.0f / 256.0f);
    float e2 = (red[4] + red[5] + red[6] + red[7]) * (1.0f / 256.0f);
    float rst = rsqrtf(e2 - m * m + LNEPS);
    s_s[tid] = (x - m) * rst * g[tid] + bvec[tid];
    __syncthreads();
    float acc = 0.f;
#pragma unroll 4
    for (int d = 0; d < 256; d++) acc += s_s[d] * Wq[(size_t)d * 256 + tid];
    int b = row >> 3, q = row & 7;
    qp[((size_t)(b * 4 + (tid >> 6)) * 8 + q) * 64 + (tid & 63)] = acc;
}

// -------- fused attention v5 (round 12, unchanged) --------
__global__ __launch_bounds__(256) void attn_fused_kernel(const ushort_t* __restrict__ kv,
                                                         const float* __restrict__ qp,
                                                         float* __restrict__ Upart,
                                                         float* __restrict__ Cpart,
                                                         float* __restrict__ vis,
                                                         int write_vis) {
    int b = blockIdx.y;
    int chunk = blockIdx.x;
    int tid = threadIdx.x;
    __shared__ __align__(16) ushort_t qfrag[16 * 512];  // 16 KB
    __shared__ float att[128][32];                      // 16 KB
    __shared__ float ubuf[2][2048];                     // 16 KB
    __shared__ float cred[8][32];

    {
        const float* qb_ = qp + (size_t)b * 2048;
#pragma unroll
        for (int snt = 0; snt < 16; snt++) {
            int s = snt >> 1, nt = snt & 1;
#pragma unroll
            for (int rep = 0; rep < 2; rep++) {
                int idx = tid + rep * 256;  // 0..511
                int k  = s * 32 + ((idx >> 7) << 3) + (idx & 7);
                int hq = nt * 16 + ((idx >> 3) & 15);
                float v = ((k >> 6) == (hq >> 3))
                              ? qb_[(hq >> 3) * 512 + (hq & 7) * 64 + (k & 63)] : 0.f;
                qfrag[snt * 512 + idx] = f2bf(v);
            }
        }
    }
    __syncthreads();

    const int w = tid >> 6, l = tid & 63;
    const int lr = l & 15, kc8 = (l >> 4) * 8;
    const int h_u = l >> 4, d4 = l & 15;
    const int uo = h_u * 64 + d4 * 4;
    const ushort_t* vbase = kv + (size_t)(b * 1024 + chunk * 128 + w * 32) * 512 + 256 + uo;

    short8 qb2[2][8];
#pragma unroll
    for (int s = 0; s < 8; s++) {
        qb2[0][s] = *(const short8*)&qfrag[(s * 2 + 0) * 512 + l * 8];
        qb2[1][s] = *(const short8*)&qfrag[(s * 2 + 1) * 512 + l * 8];
    }
    f32x4 zero = {0.f, 0.f, 0.f, 0.f};
#pragma unroll
    for (int mi_loc = 0; mi_loc < 2; mi_loc++) {
        int mi = w * 2 + mi_loc;
        f32x4 a0 = zero, a1 = zero;
        const ushort_t* abase = kv + (size_t)(b * 1024 + chunk * 128 + mi * 16 + lr) * 512 + kc8;
#pragma unroll
        for (int s = 0; s < 8; s++) {
            short8 af = *(const short8*)(abase + s * 32);
            a0 = mfma_bf16(af, qb2[0][s], a0);
            a1 = mfma_bf16(af, qb2[1][s], a1);
        }
        int row0 = mi * 16 + (l >> 4) * 4;
#pragma unroll
        for (int r = 0; r < 4; r++) {
            att[row0 + r][lr]      = a0[r];
            att[row0 + r][16 + lr] = a1[r];
        }
    }
    uint2 vpre[8];
#pragma unroll
    for (int i = 0; i < 8; i++)
        vpre[i] = *(const uint2*)(vbase + (size_t)i * 512);
    __syncthreads();

    {
        int token = tid >> 1, half = tid & 1;
        float v[16];
        float mx = -3.4e38f;
#pragma unroll
        for (int j = 0; j < 16; j++) { v[j] = att[token][half * 16 + j]; mx = fmaxf(mx, v[j]); }
        mx = fmaxf(mx, __shfl_xor(mx, 1));
        float sm = 0.f;
#pragma unroll
        for (int j = 0; j < 16; j++) { v[j] = __expf(v[j] - mx); sm += v[j]; }
        sm += __shfl_xor(sm, 1);
        float inv = 1.0f / sm;
#pragma unroll
        for (int j = 0; j < 16; j++) { v[j] *= inv; att[token][half * 16 + j] = v[j] + EPS_; }
        if (write_vis) {
#pragma unroll
            for (int q = 0; q < 8; q++) {
                float pv = v[q] + v[q + 8];
                float pf = pv + __shfl_xor(pv, 1);
                if (half == 0) vis[(size_t)(b * 8 + q) * 1024 + chunk * 128 + token] = pf;
            }
        }
    }
    __syncthreads();

    {
        int hq2 = tid & 31, grp = tid >> 5;
        float s = 0.f;
#pragma unroll
        for (int i = 0; i < 16; i++) s += att[grp * 16 + i][hq2];
        cred[grp][hq2] = s;
    }
    __syncthreads();
    if (tid < 32) {
        float s = 0.f;
#pragma unroll
        for (int g2 = 0; g2 < 8; g2++) s += cred[g2][tid];
        Cpart[(size_t)(b * 8 + chunk) * 32 + tid] = s;
    }

    float U[8][4];
#pragma unroll
    for (int q = 0; q < 8; q++)
#pragma unroll
        for (int d = 0; d < 4; d++) U[q][d] = 0.f;
    for (int c4 = 0; c4 < 4; ++c4) {
        uint2 vnx[8];
        if (c4 < 3) {
#pragma unroll
            for (int i = 0; i < 8; i++)
                vnx[i] = *(const uint2*)(vbase + (size_t)((c4 + 1) * 8 + i) * 512);
        }
#pragma unroll
        for (int i2 = 0; i2 < 8; i2++) {
            uint2 vp = vpre[i2];
            float v0 = bf2f(vp.x & 0xffffu), v1 = bf2f(vp.x >> 16);
            float v2 = bf2f(vp.y & 0xffffu), v3 = bf2f(vp.y >> 16);
            const float* arow = &att[w * 32 + c4 * 8 + i2][h_u * 8];
            float4 a01 = *(const float4*)(arow);
            float4 a23 = *(const float4*)(arow + 4);
            float aq[8] = {a01.x, a01.y, a01.z, a01.w, a23.x, a23.y, a23.z, a23.w};
#pragma unroll
            for (int q = 0; q < 8; q++) {
                U[q][0] += aq[q] * v0; U[q][1] += aq[q] * v1;
                U[q][2] += aq[q] * v2; U[q][3] += aq[q] * v3;
            }
        }
        if (c4 < 3) {
#pragma unroll
            for (int i = 0; i < 8; i++) vpre[i] = vnx[i];
        }
    }
    if (w & 1) {
        float* dst = ubuf[w >> 1];
#pragma unroll
        for (int q = 0; q < 8; q++) {
            float4 uq = {U[q][0], U[q][1], U[q][2], U[q][3]};
            *(float4*)(dst + q * 256 + uo) = uq;
        }
    }
    __syncthreads();
    if (!(w & 1)) {
        const float* src = ubuf[w >> 1];
#pragma unroll
        for (int q = 0; q < 8; q++) {
            float4 uq = *(const float4*)(src + q * 256 + uo);
            U[q][0] += uq.x; U[q][1] += uq.y; U[q][2] += uq.z; U[q][3] += uq.w;
        }
    }
    __syncthreads();
    if (w == 2) {
        float* dst = ubuf[0];
#pragma unroll
        for (int q = 0; q < 8; q++) {
            float4 uq = {U[q][0], U[q][1], U[q][2], U[q][3]};
            *(float4*)(dst + q * 256 + uo) = uq;
        }
    }
    __syncthreads();
    if (w == 0) {
        const float* src = ubuf[0];
        float* up = Upart + (size_t)(b * 8 + chunk) * 2048 + uo;
#pragma unroll
        for (int q = 0; q < 8; q++) {
            float4 uq = *(const float4*)(src + q * 256 + uo);
            float4 o = {U[q][0] + uq.x, U[q][1] + uq.y, U[q][2] + uq.z, U[q][3] + uq.w};
            *(float4*)(up + q * 256) = o;
        }
    }
}

// -------- fused slot update v6: f16 dot2 GEMVs, 1024 threads --------
// 256 blocks x 1024 threads; 2 rows per block.
__global__ __launch_bounds__(1024) void slot_fused_kernel(const float* __restrict__ Upart,
                                                          const float* __restrict__ Cpart,
                                                          const float* __restrict__ slotsIn,
                                                          const unsigned int* __restrict__ wgp,
                                                          const float* __restrict__ b_ih,
                                                          const float* __restrict__ b_hh,
                                                          const float* __restrict__ ln_mlp_g,
                                                          const float* __restrict__ ln_mlp_b,
                                                          const unsigned int* __restrict__ w1pp,
                                                          const float* __restrict__ b1,
                                                          const unsigned int* __restrict__ w2pp,
                                                          const float* __restrict__ b2,
                                                          const float* __restrict__ ln_sl_g,
                                                          const float* __restrict__ ln_sl_b,
                                                          const unsigned int* __restrict__ Wqpp,
                                                          float* __restrict__ slotsOut,
                                                          float* __restrict__ qp,
                                                          int emit_qp) {
    __shared__ float Uf[2][256], Hf[2][256];
    __shared__ unsigned int Upk[2][128], Hpk[2][128];
    __shared__ float rsum[2][2][256];
    __shared__ float gpart[2][12][256];
    __shared__ float SB_s[2][256];
    __shared__ float Mf[2][256];
    __shared__ unsigned int Mpk[2][128];
    __shared__ float mpart[2][2][512];
    __shared__ float hidf[2][512];
    __shared__ unsigned int hidpk[2][256];
    __shared__ float ppart[4][2][256];
    __shared__ float redA[8], redB[8];
    const int t = threadIdx.x;
    const int kh = t >> 9, s9 = t & 511;
    const int rr = s9 >> 8, c = s9 & 255;
    const int lane = t & 63, wvi = t >> 6;
    const int r0 = blockIdx.x * 2;
    const int rg = r0 + rr, bb_ = rg >> 3, q = rg & 7;

    // ---- phase 0: Upart reduce + normalize; emit f32 + packed f16 acts ----
    {
        float s = 0.f;
#pragma unroll
        for (int p2 = 0; p2 < 4; p2++)
            s += Upart[(size_t)(bb_ * 8 + kh * 4 + p2) * 2048 + q * 256 + c];
        rsum[kh][rr][c] = s;
    }
    __syncthreads();
    if (kh == 0) {
        int h = c >> 6;
        float C = 0.f;
#pragma unroll
        for (int p2 = 0; p2 < 8; p2++)
            C += Cpart[(size_t)(bb_ * 8 + p2) * 32 + h * 8 + q];
        Uf[rr][c] = (rsum[0][rr][c] + rsum[1][rr][c]) / C;
        Hf[rr][c] = slotsIn[(size_t)rg * 256 + c];
    }
    __syncthreads();
    if (t < 512) {
        int arr = t >> 8, rem = t & 255;
        int rr2 = rem >> 7, pr = rem & 127;
        if (arr == 0) Upk[rr2][pr] = pkh(Uf[rr2][2 * pr], Uf[rr2][2 * pr + 1]);
        else          Hpk[rr2][pr] = pkh(Hf[rr2][2 * pr], Hf[rr2][2 * pr + 1]);
    }
    __syncthreads();

    // ---- GRU GEMV (f16 dot2): thread (kh, mh=rr, c); k2 in [kh*64, kh*64+64) ----
    {
        float ar0, az0, an0;
        if (kh == 0) {
            const float* bias = rr ? b_hh : b_ih;
            ar0 = bias[c]; az0 = bias[256 + c]; an0 = bias[512 + c];
        } else { ar0 = az0 = an0 = 0.f; }
        float ar1 = ar0, az1 = az0, an1 = an0;
        const unsigned int (*Apk)[128] = rr ? Hpk : Upk;
        const unsigned int* wp = wgp + ((size_t)(kh * 64) * 512 + s9) * 4;
        for (int cc = 0; cc < 8; cc++) {
            uint4 wreg[8];
#pragma unroll
            for (int i = 0; i < 8; i++)
                wreg[i] = *(const uint4*)(wp + (size_t)(cc * 8 + i) * 2048);
#pragma unroll
            for (int i = 0; i < 8; i++) {
                int k2 = kh * 64 + cc * 8 + i;
                unsigned int a0 = Apk[0][k2], a1 = Apk[1][k2];
                ar0 = fdot2(a0, wreg[i].x, ar0);
                az0 = fdot2(a0, wreg[i].y, az0);
                an0 = fdot2(a0, wreg[i].z, an0);
                ar1 = fdot2(a1, wreg[i].x, ar1);
                az1 = fdot2(a1, wreg[i].y, az1);
                an1 = fdot2(a1, wreg[i].z, an1);
            }
        }
        gpart[kh][rr * 6 + 0][c] = ar0; gpart[kh][rr * 6 + 1][c] = ar1;
        gpart[kh][rr * 6 + 2][c] = az0; gpart[kh][rr * 6 + 3][c] = az1;
        gpart[kh][rr * 6 + 4][c] = an0; gpart[kh][rr * 6 + 5][c] = an1;
    }
    __syncthreads();

    // ---- gates + LN(mlp): kh==0 threads ----
    float sb = 0.f;
    if (kh == 0) {
        float xr = gpart[0][0 + rr][c] + gpart[1][0 + rr][c];
        float xz = gpart[0][2 + rr][c] + gpart[1][2 + rr][c];
        float xn = gpart[0][4 + rr][c] + gpart[1][4 + rr][c];
        float hr = gpart[0][6 + rr][c] + gpart[1][6 + rr][c];
        float hz = gpart[0][8 + rr][c] + gpart[1][8 + rr][c];
        float hn = gpart[0][10 + rr][c] + gpart[1][10 + rr][c];
        float rg_ = 1.f / (1.f + __expf(-(xr + hr)));
        float z   = 1.f / (1.f + __expf(-(xz + hz)));
        float nn  = tanhf(xn + rg_ * hn);
        sb = (1.f - z) * nn + z * Hf[rr][c];
        SB_s[rr][c] = sb;
        float s1 = wred_sum(sb), s2 = wred_sum(sb * sb);
        if (lane == 0) { redA[wvi] = s1; redB[wvi] = s2; }
    }
    __syncthreads();
    if (kh == 0) {
        int base = rr * 4;
        float m  = (redA[base] + redA[base + 1] + redA[base + 2] + redA[base + 3]) * (1.f / 256.f);
        float e2 = (redB[base] + redB[base + 1] + redB[base + 2] + redB[base + 3]) * (1.f / 256.f);
        float rst = rsqrtf(e2 - m * m + LNEPS);
        Mf[rr][c] = (sb - m) * rst * ln_mlp_g[c] + ln_mlp_b[c];
    }
    __syncthreads();
    if (t < 256) {
        int rr2 = t >> 7, pr = t & 127;
        Mpk[rr2][pr] = pkh(Mf[rr2][2 * pr], Mf[rr2][2 * pr + 1]);
    }
    __syncthreads();

    // ---- MLP1 (f16 dot2): thread (kh, j=s9); k2 in [kh*64, kh*64+64) ----
    {
        float h10 = 0.f, h11 = 0.f;
        const unsigned int* wp = w1pp + (size_t)(kh * 64) * 512 + s9;
        for (int cc = 0; cc < 4; cc++) {
            unsigned int wreg[16];
#pragma unroll
            for (int i = 0; i < 16; i++)
                wreg[i] = wp[(size_t)(cc * 16 + i) * 512];
#pragma unroll
            for (int i = 0; i < 16; i++) {
                int k2 = kh * 64 + cc * 16 + i;
                h10 = fdot2(Mpk[0][k2], wreg[i], h10);
                h11 = fdot2(Mpk[1][k2], wreg[i], h11);
            }
        }
        mpart[kh][0][s9] = h10;
        mpart[kh][1][s9] = h11;
    }
    __syncthreads();
    if (kh == 0) {
        float bb1 = b1[s9];
        hidf[0][s9] = fmaxf(mpart[0][0][s9] + mpart[1][0][s9] + bb1, 0.f);
        hidf[1][s9] = fmaxf(mpart[0][1][s9] + mpart[1][1][s9] + bb1, 0.f);
    }
    __syncthreads();
    if (t < 512) {
        int r2 = t >> 8, pr = t & 255;
        hidpk[r2][pr] = pkh(hidf[r2][2 * pr], hidf[r2][2 * pr + 1]);
    }
    __syncthreads();

    // ---- MLP2 (f16 dot2): thread (q2=kh*2+rr, c); k2 in [q2*64, q2*64+64) ----
    {
        int q2 = kh * 2 + rr;
        float p0 = 0.f, p1 = 0.f;
        const unsigned int* wp = w2pp + (size_t)(q2 * 64) * 256 + c;
        for (int cc = 0; cc < 4; cc++) {
            unsigned int wreg[16];
#pragma unroll
            for (int i = 0; i < 16; i++)
                wreg[i] = wp[(size_t)(cc * 16 + i) * 256];
#pragma unroll
            for (int i = 0; i < 16; i++) {
                int k2 = q2 * 64 + cc * 16 + i;
                p0 = fdot2(hidpk[0][k2], wreg[i], p0);
                p1 = fdot2(hidpk[1][k2], wreg[i], p1);
            }
        }
        ppart[q2][0][c] = p0;
        ppart[q2][1][c] = p1;
    }
    __syncthreads();
    float outv = 0.f;
    if (kh == 0) {
        outv = ppart[0][rr][c] + ppart[1][rr][c] + ppart[2][rr][c] + ppart[3][rr][c]
             + b2[c] + SB_s[rr][c];
        slotsOut[(size_t)rg * 256 + c] = outv;
    }

    if (emit_qp) {
        __syncthreads();
        if (kh == 0) {
            float s1 = wred_sum(outv), s2 = wred_sum(outv * outv);
            if (lane == 0) { redA[wvi] = s1; redB[wvi] = s2; }
        }
        __syncthreads();
        if (kh == 0) {
            int base = rr * 4;
            float m  = (redA[base] + redA[base + 1] + redA[base + 2] + redA[base + 3]) * (1.f / 256.f);
            float e2 = (redB[base] + redB[base + 1] + redB[base + 2] + redB[base + 3]) * (1.f / 256.f);
            float rst = rsqrtf(e2 - m * m + LNEPS);
            Mf[rr][c] = (outv - m) * rst * ln_sl_g[c] + ln_sl_b[c];
        }
        __syncthreads();
        if (t < 256) {
            int rr2 = t >> 7, pr = t & 127;
            Mpk[rr2][pr] = pkh(Mf[rr2][2 * pr], Mf[rr2][2 * pr + 1]);
        }
        __syncthreads();
        {
            int q2 = kh * 2 + rr;
            float p0 = 0.f, p1 = 0.f;
            const unsigned int* wp = Wqpp + (size_t)(q2 * 32) * 256 + c;
            for (int cc = 0; cc < 2; cc++) {
                unsigned int wreg[16];
#pragma unroll
                for (int i = 0; i < 16; i++)
                    wreg[i] = wp[(size_t)(cc * 16 + i) * 256];
#pragma unroll
                for (int i = 0; i < 16; i++) {
                    int k2 = q2 * 32 + cc * 16 + i;
                    p0 = fdot2(Mpk[0][k2], wreg[i], p0);
                    p1 = fdot2(Mpk[1][k2], wreg[i], p1);
                }
            }
            ppart[q2][0][c] = p0;
            ppart[q2][1][c] = p1;
        }
        __syncthreads();
        if (kh == 0) {
            float qv = ppart[0][rr][c] + ppart[1][rr][c] + ppart[2][rr][c] + ppart[3][rr][c];
            qp[(size_t)bb_ * 2048 + (c >> 6) * 512 + q * 64 + (c & 63)] = qv;
        }
    }
}

// -------- host --------
extern "C" void kernel_launch(void* const* d_in, const int* in_sizes, int n_in,
                              void* d_out, int out_size, void* d_ws, size_t ws_size,
                              hipStream_t stream) {
    const float* inputs   = (const float*)d_in[0];
    const float* slots0   = (const float*)d_in[1];
    const float* ln_in_g  = (const float*)d_in[2];
    const float* ln_in_b  = (const float*)d_in[3];
    const float* ln_sl_g  = (const float*)d_in[4];
    const float* ln_sl_b  = (const float*)d_in[5];
    const float* ln_mlp_g = (const float*)d_in[6];
    const float* ln_mlp_b = (const float*)d_in[7];
    const float* Wq       = (const float*)d_in[8];
    const float* Wk       = (const float*)d_in[9];
    const float* Wv       = (const float*)d_in[10];
    const float* w_ih     = (const float*)d_in[11];
    const float* w_hh     = (const float*)d_in[12];
    const float* b_ih     = (const float*)d_in[13];
    const float* b_hh     = (const float*)d_in[14];
    const float* w1       = (const float*)d_in[15];
    const float* b1       = (const float*)d_in[16];
    const float* w2       = (const float*)d_in[17];
    const float* b2       = (const float*)d_in[18];

    float* out_slots = (float*)d_out;
    float* out_vis   = (float*)d_out + 64 * 8 * 256;

    char* p = (char*)d_ws;
    auto carve = [&](size_t bytes) {
        void* r = (void*)p;
        p += (bytes + 255) & ~(size_t)255;
        return r;
    };
    ushort_t* kv    = (ushort_t*)carve((size_t)65536 * 512 * 2);   // 64 MB
    ushort_t* Wt    = (ushort_t*)carve((size_t)512 * 256 * 2);
    ushort_t* Wtp   = (ushort_t*)carve((size_t)512 * 256 * 2);
    unsigned int* wgp  = (unsigned int*)carve((size_t)128 * 512 * 4 * 4);  // 1 MB
    unsigned int* w1pp = (unsigned int*)carve((size_t)128 * 512 * 4);      // 256 KB
    unsigned int* w2pp = (unsigned int*)carve((size_t)256 * 256 * 4);      // 256 KB
    unsigned int* Wqpp = (unsigned int*)carve((size_t)128 * 256 * 4);      // 128 KB
    float* qp       = (float*)carve((size_t)64 * 2048 * 4);
    float* Upart    = (float*)carve((size_t)64 * 8 * 2048 * 4);    // 4 MB
    float* Cpart    = (float*)carve((size_t)64 * 8 * 32 * 4);
    float* slotsA   = (float*)carve((size_t)512 * 256 * 4);

    prepack_w_kernel<<<512, 256, 0, stream>>>(Wk, Wv, Wt);
    prepack_wtp_kernel<<<64, 256, 0, stream>>>(Wt, Wtp);
    prepack_slotw_kernel<<<dim3(256, 4), 512, 0, stream>>>(w_ih, w_hh, w1, w2, Wq,
                                                           wgp, w1pp, w2pp, Wqpp);
    kvproj_mfma_kernel<<<1024, 512, 0, stream>>>(inputs, ln_in_g, ln_in_b, Wtp, kv);
    qproj_kernel<<<512, 256, 0, stream>>>(slots0, ln_sl_g, ln_sl_b, Wq, qp);

    for (int it = 0; it < 3; ++it) {
        attn_fused_kernel<<<dim3(8, 64), 256, 0, stream>>>(kv, qp, Upart, Cpart, out_vis,
                                                           (it == 2) ? 1 : 0);
        slot_fused_kernel<<<256, 1024, 0, stream>>>(
            Upart, Cpart, (it == 0) ? slots0 : slotsA,
            wgp, b_ih, b_hh, ln_mlp_g, ln_mlp_b, w1pp, b1, w2pp, b2,
            ln_sl_g, ln_sl_b, Wqpp,
            (it == 2) ? out_slots : slotsA, qp, (it < 2) ? 1 : 0);
    }
}